// Round 4
// baseline (412.217 us; speedup 1.0000x reference)
//
#include <hip/hip_runtime.h>
#include <hip/hip_bf16.h>

#define MROWS 16384   // B*L
#define DDIM  512
#define HDIM  1024
#define CDIM  8192
#define LN_EPS 1e-5f
#define CAND_MAX 64
#define SCORE_DELTA 3.0f
#define RESCORE_WIN 3.0f

typedef __attribute__((ext_vector_type(8))) short bf16x8;
typedef __attribute__((ext_vector_type(4))) float f32x4;

__device__ __forceinline__ unsigned int f2key(float f) {
  unsigned int b = __float_as_uint(f);
  return (b & 0x80000000u) ? ~b : (b | 0x80000000u);
}
__device__ __forceinline__ float key2f(unsigned int k) {
  unsigned int b = (k & 0x80000000u) ? (k ^ 0x80000000u) : ~k;
  return __uint_as_float(b);
}

// ---------------- LayerNorm -> bf16 (one wave per row, 4 rows/block) ----------
__global__ __launch_bounds__(256) void k_ln(const float* __restrict__ x,
                                            const float* __restrict__ lnw,
                                            const float* __restrict__ lnb,
                                            __hip_bfloat16* __restrict__ xb) {
  const int row = blockIdx.x * 4 + (threadIdx.x >> 6);
  const int t = threadIdx.x & 63;
  const float4* xr = (const float4*)(x + (size_t)row * DDIM);
  float4 v0 = xr[2 * t + 0];
  float4 v1 = xr[2 * t + 1];
  float s = v0.x + v0.y + v0.z + v0.w + v1.x + v1.y + v1.z + v1.w;
#pragma unroll
  for (int m = 1; m < 64; m <<= 1) s += __shfl_xor(s, m, 64);
  const float mu = s * (1.0f / DDIM);
  float a0 = v0.x - mu, a1 = v0.y - mu, a2 = v0.z - mu, a3 = v0.w - mu;
  float a4 = v1.x - mu, a5 = v1.y - mu, a6 = v1.z - mu, a7 = v1.w - mu;
  float q = a0*a0 + a1*a1 + a2*a2 + a3*a3 + a4*a4 + a5*a5 + a6*a6 + a7*a7;
#pragma unroll
  for (int m = 1; m < 64; m <<= 1) q += __shfl_xor(q, m, 64);
  const float inv = rsqrtf(q * (1.0f / DDIM) + LN_EPS);
  const float4* wr = (const float4*)lnw;
  const float4* br = (const float4*)lnb;
  float4 w0 = wr[2*t+0], w1 = wr[2*t+1];
  float4 b0 = br[2*t+0], b1 = br[2*t+1];
  float y[8];
  y[0] = a0*inv*w0.x + b0.x;  y[1] = a1*inv*w0.y + b0.y;
  y[2] = a2*inv*w0.z + b0.z;  y[3] = a3*inv*w0.w + b0.w;
  y[4] = a4*inv*w1.x + b1.x;  y[5] = a5*inv*w1.y + b1.y;
  y[6] = a6*inv*w1.z + b1.z;  y[7] = a7*inv*w1.w + b1.w;
  union { unsigned short u[8]; uint4 v4; } o;
#pragma unroll
  for (int i = 0; i < 8; ++i) {
    union { __hip_bfloat16 h; unsigned short us; } cv;
    cv.h = __float2bfloat16(y[i]);
    o.u[i] = cv.us;
  }
  *(uint4*)(xb + (size_t)row * DDIM + 8 * t) = o.v4;
}

// ---------------- c_sq[c] = sum_h cb[h][c]^2 (fp64 accumulate) ----------------
__global__ __launch_bounds__(256) void k_csq(const float* __restrict__ cb,
                                             float* __restrict__ csq_f,
                                             double* __restrict__ csq_d) {
  const int c = blockIdx.x * 256 + threadIdx.x;
  double a = 0.0;
  for (int h = 0; h < HDIM; ++h) {
    float v = cb[(size_t)h * CDIM + c];
    a += (double)v * (double)v;
  }
  csq_f[c] = (float)a;
  csq_d[c] = a;
}

// ------- Gt[n][d] = sum_h W[h][d]*cb[h][n] (fp32; 128x128 tile, 8x8/thread) ---
// Per-element accumulation order is IDENTICAL to the previous version:
// h-chunks of 32 ascending, sequential fmaf within chunk, per-chunk
// sub-accumulator added into the master accumulator.
__global__ __launch_bounds__(256) void k_gproj(const float* __restrict__ W,
                                               const float* __restrict__ cb,
                                               float* __restrict__ Gt,
                                               __hip_bfloat16* __restrict__ Gtb) {
  __shared__ float Ws[32][128];   // [h][d]
  __shared__ float Cs[32][128];   // [h][n]
  const int tx = threadIdx.x;     // 16, d-sub
  const int ty = threadIdx.y;     // 16, n-sub
  const int n0 = blockIdx.x * 128;
  const int d0 = blockIdx.y * 128;
  const int lin = ty * 16 + tx;
  float accm[8][8];               // [n][d]
#pragma unroll
  for (int j = 0; j < 8; ++j)
#pragma unroll
    for (int i = 0; i < 8; ++i) accm[j][i] = 0.0f;

  for (int h0 = 0; h0 < HDIM; h0 += 32) {
    __syncthreads();
#pragma unroll
    for (int i = 0; i < 4; ++i) {
      int f = lin + 256 * i;
      int hh = f >> 5, e4 = f & 31;
      ((float4*)&Ws[hh][0])[e4] = ((const float4*)(W  + (size_t)(h0 + hh) * DDIM + d0))[e4];
      ((float4*)&Cs[hh][0])[e4] = ((const float4*)(cb + (size_t)(h0 + hh) * CDIM + n0))[e4];
    }
    __syncthreads();
    float accs[8][8];
#pragma unroll
    for (int j = 0; j < 8; ++j)
#pragma unroll
      for (int i = 0; i < 8; ++i) accs[j][i] = 0.0f;
#pragma unroll
    for (int k = 0; k < 32; ++k) {
      float4 av0 = ((const float4*)&Ws[k][0])[tx];
      float4 av1 = ((const float4*)&Ws[k][0])[tx + 16];
      float4 bv0 = ((const float4*)&Cs[k][0])[ty];
      float4 bv1 = ((const float4*)&Cs[k][0])[ty + 16];
      float aa[8] = {av0.x, av0.y, av0.z, av0.w, av1.x, av1.y, av1.z, av1.w};
      float bb[8] = {bv0.x, bv0.y, bv0.z, bv0.w, bv1.x, bv1.y, bv1.z, bv1.w};
#pragma unroll
      for (int j = 0; j < 8; ++j)
#pragma unroll
        for (int i = 0; i < 8; ++i) accs[j][i] = fmaf(bb[j], aa[i], accs[j][i]);
    }
#pragma unroll
    for (int j = 0; j < 8; ++j)
#pragma unroll
      for (int i = 0; i < 8; ++i) accm[j][i] += accs[j][i];
  }
#pragma unroll
  for (int j = 0; j < 8; ++j) {
    const int n = n0 + ty * 4 + (j >> 2) * 64 + (j & 3);
#pragma unroll
    for (int di = 0; di < 2; ++di) {
      float4 o = make_float4(accm[j][di*4+0], accm[j][di*4+1], accm[j][di*4+2], accm[j][di*4+3]);
      ((float4*)(Gt + (size_t)n * DDIM + d0))[tx + di * 16] = o;
      union { __hip_bfloat16 h; unsigned short us; } c0, c1, c2, c3;
      c0.h = __float2bfloat16(o.x); c1.h = __float2bfloat16(o.y);
      c2.h = __float2bfloat16(o.z); c3.h = __float2bfloat16(o.w);
      ((ushort4*)(Gtb + (size_t)n * DDIM + d0))[tx + di * 16] = make_ushort4(c0.us, c1.us, c2.us, c3.us);
    }
  }
}

// ================= 8-phase 256x256 MFMA scoring kernel =================
// LDS: A(buf,kh) at buf*32768+kh*16384: [256 rows][32 k] bf16 (64B rows,
// 4x16B slots). Bank-quad swizzle: physical slot p = g ^ ((row>>1)&3) --
// any 8 consecutive rows at one logical slot map to all 8 bank-quads
// (zero ds_read_b128 conflicts). gload_lds dest stays LINEAR; the swizzle
// is applied to the per-lane GLOBAL source slot (rule: both-sides swizzle).

#define NOISSUE ((void)0)

#define STAGE(GB, REGOFF, KT, KH) { \
  const unsigned short* s0_ = (GB) + (size_t)sr0 * 512 + ((KT)*64 + (KH)*32 + sce*8); \
  const unsigned short* s1_ = (GB) + (size_t)sr1 * 512 + ((KT)*64 + (KH)*32 + sce*8); \
  __builtin_amdgcn_global_load_lds((const __attribute__((address_space(1))) unsigned int*)s0_, \
      (__attribute__((address_space(3))) unsigned int*)(lds + (REGOFF) + t*16), 16, 0, 0); \
  __builtin_amdgcn_global_load_lds((const __attribute__((address_space(1))) unsigned int*)s1_, \
      (__attribute__((address_space(3))) unsigned int*)(lds + (REGOFF) + 8192 + t*16), 16, 0, 0); }

#define FRAG_A(BUF,KH,MH) { \
  const char* Ab_ = lds + (BUF)*32768 + (KH)*16384 + (MH)*4096; \
  _Pragma("unroll") for (int mi_ = 0; mi_ < 4; ++mi_) \
    a[mi_] = *(const bf16x8*)(Ab_ + aoff + mi_*1024); }

#define FRAG_B(BUF,KH) { \
  const char* Bb_ = lds + 65536 + (BUF)*32768 + (KH)*16384; \
  _Pragma("unroll") for (int ni_ = 0; ni_ < 4; ++ni_) \
    b[ni_] = *(const bf16x8*)(Bb_ + boff + ni_*1024); }

#define MFMA16(MH) { \
  _Pragma("unroll") for (int mi_ = 0; mi_ < 4; ++mi_) \
  _Pragma("unroll") for (int ni_ = 0; ni_ < 4; ++ni_) \
    acc[(MH)*4+mi_][ni_] = __builtin_amdgcn_mfma_f32_16x16x32_bf16(a[mi_], b[ni_], acc[(MH)*4+mi_][ni_], 0, 0, 0); }

#define PHASE(BUF,KH,MH, ISSUE, WAITSTR) do { \
  FRAG_A(BUF,KH,MH); \
  if ((MH) == 0) { FRAG_B(BUF,KH); } \
  ISSUE; \
  asm volatile("s_waitcnt " WAITSTR ::: "memory"); \
  __builtin_amdgcn_s_barrier(); \
  __builtin_amdgcn_sched_barrier(0); \
  __builtin_amdgcn_s_setprio(1); \
  MFMA16(MH); \
  __builtin_amdgcn_s_setprio(0); \
  __builtin_amdgcn_sched_barrier(0); \
  __builtin_amdgcn_s_barrier(); \
  __builtin_amdgcn_sched_barrier(0); \
} while (0)

__global__ __launch_bounds__(512, 2) void k_score(
    const __hip_bfloat16* __restrict__ xb,   // [16384][512]
    const __hip_bfloat16* __restrict__ Gtb,  // [8192][512]
    const float* __restrict__ csq,           // [8192]
    unsigned int* __restrict__ rowminG,      // [16384] key-encoded, init 0xFF
    unsigned int* __restrict__ cnt,          // [16384]
    int* __restrict__ candI,                 // [16384][CAND_MAX]
    float* __restrict__ candS)               // [16384][CAND_MAX]
{
  __shared__ __align__(16) char lds[131072];
  __shared__ unsigned int rowthr[256];

  const int t = threadIdx.x;
  const int wave = t >> 6;
  const int lane = t & 63;
  const int l15 = lane & 15;
  const int l4  = lane >> 4;
  const int wm = wave >> 2;   // 2 waves in M
  const int wn = wave & 3;    // 4 waves in N

  // n-major block order + bijective XCD-chunked swizzle (2048 % 8 == 0)
  const int bid = blockIdx.x;
  const int sbid = (bid & 7) * 256 + (bid >> 3);
  const int n_blk = sbid >> 6;   // 0..31
  const int m_blk = sbid & 63;   // 0..63
  const int rowbase = m_blk * 256;
  const int colbase = n_blk * 256;

  const unsigned short* gA = (const unsigned short*)xb  + (size_t)rowbase * 512;
  const unsigned short* gB = (const unsigned short*)Gtb + (size_t)colbase * 512;

  const int sr0 = t >> 2;
  const int sr1 = sr0 + 128;
  const int sce = (t & 3) ^ ((t >> 3) & 3);   // inverse-swizzled global slot

  if (t < 256) rowthr[t] = 0xFFFFFFFFu;

  const int swz = ((l4 ^ ((l15 >> 1) & 3)) << 4);
  const int aoff = wm * 8192 + l15 * 64 + swz;
  const int boff = wn * 4096 + l15 * 64 + swz;

  f32x4 acc[8][4];
#pragma unroll
  for (int i = 0; i < 8; ++i)
#pragma unroll
    for (int j = 0; j < 4; ++j) acc[i][j] = (f32x4){0.f, 0.f, 0.f, 0.f};

  bf16x8 a[4], b[4];

  // ---- prologue: K-tile 0 (4 halves) + 3 halves of K-tile 1 ----
  STAGE(gB, 65536 +     0, 0, 0);   // Bh0(0)
  STAGE(gA,             0, 0, 0);   // Ah0(0)
  STAGE(gB, 65536 + 16384, 0, 1);   // Bh1(0)
  STAGE(gA,         16384, 0, 1);   // Ah1(0)
  STAGE(gB, 65536 + 32768, 1, 0);   // Bh0(1)
  STAGE(gA,         32768, 1, 0);   // Ah0(1)
  STAGE(gB, 65536 + 49152, 1, 1);   // Bh1(1)
  asm volatile("s_waitcnt vmcnt(6)" ::: "memory");   // K-tile 0 resident
  __builtin_amdgcn_s_barrier();
  __builtin_amdgcn_sched_barrier(0);

  // ---- main loop: K-tiles 0..5 (iterations 0..2) ----
#pragma unroll
  for (int it_ = 0; it_ < 3; ++it_) {
    const int T = 2 * it_;
    PHASE(0,0,0, STAGE(gA,         49152, T+1, 1), "vmcnt(10)");  // Ah1(T+1)
    PHASE(0,0,1, STAGE(gB, 65536 +     0, T+2, 0), "vmcnt(10)");  // Bh0(T+2)
    PHASE(0,1,0, STAGE(gA,             0, T+2, 0), "vmcnt(10)");  // Ah0(T+2)
    PHASE(0,1,1, STAGE(gB, 65536 + 16384, T+2, 1), "vmcnt(10)");  // Bh1(T+2)
    PHASE(1,0,0, STAGE(gA,         16384, T+2, 1), "vmcnt(10)");  // Ah1(T+2)
    PHASE(1,0,1, STAGE(gB, 65536 + 32768, T+3, 0), "vmcnt(10)");  // Bh0(T+3)
    PHASE(1,1,0, STAGE(gA,         32768, T+3, 0), "vmcnt(10)");  // Ah0(T+3)
    PHASE(1,1,1, STAGE(gB, 65536 + 49152, T+3, 1), "vmcnt(10)");  // Bh1(T+3)
  }
  // ---- tail: K-tiles 6,7 ----
  PHASE(0,0,0, STAGE(gA, 49152, 7, 1), "vmcnt(10)");  // Ah1(7), last issue
  PHASE(0,0,1, NOISSUE, "vmcnt(8)");
  PHASE(0,1,0, NOISSUE, "vmcnt(8)");
  PHASE(0,1,1, NOISSUE, "vmcnt(4)");
  PHASE(1,0,0, NOISSUE, "vmcnt(4)");
  PHASE(1,0,1, NOISSUE, "vmcnt(0)");
  PHASE(1,1,0, NOISSUE, "vmcnt(0)");
  PHASE(1,1,1, NOISSUE, "vmcnt(0)");

  // ---- epilogue: s = csq - 2*dot ; block/global running min ; capture ----
  float csqv[4];
#pragma unroll
  for (int ni = 0; ni < 4; ++ni) csqv[ni] = csq[colbase + wn*64 + ni*16 + l15];

#pragma unroll
  for (int mi = 0; mi < 8; ++mi) {
#pragma unroll
    for (int r = 0; r < 4; ++r) {
      float mn = 1e30f;
#pragma unroll
      for (int ni = 0; ni < 4; ++ni) mn = fminf(mn, fmaf(-2.0f, acc[mi][ni][r], csqv[ni]));
#pragma unroll
      for (int msk = 1; msk < 16; msk <<= 1) mn = fminf(mn, __shfl_xor(mn, msk, 64));
      if (l15 == 0) {
        const int rowl = wm*128 + mi*16 + l4*4 + r;
        atomicMin(&rowthr[rowl], f2key(mn));
      }
    }
  }
  __syncthreads();
  if (t < 256) {
    unsigned int lk = rowthr[t];
    unsigned int old = atomicMin(&rowminG[rowbase + t], lk);
    if (old < lk) atomicMin(&rowthr[t], old);
  }
  __syncthreads();
#pragma unroll
  for (int mi = 0; mi < 8; ++mi) {
#pragma unroll
    for (int r = 0; r < 4; ++r) {
      const int rowl = wm*128 + mi*16 + l4*4 + r;
      const float thr = key2f(rowthr[rowl]) + SCORE_DELTA;
#pragma unroll
      for (int ni = 0; ni < 4; ++ni) {
        float sv = fmaf(-2.0f, acc[mi][ni][r], csqv[ni]);
        if (sv <= thr) {
          const int grow = rowbase + rowl;
          unsigned int old = atomicAdd(&cnt[grow], 1u);
          if (old < CAND_MAX) {
            candI[(size_t)grow * CAND_MAX + old] = colbase + wn*64 + ni*16 + l15;
            candS[(size_t)grow * CAND_MAX + old] = sv;
          }
        }
      }
    }
  }
}

// ------- exact fp32/fp64 rescore, filtered by stored bf16-MFMA scores --------
__global__ __launch_bounds__(256) void k_fixup(const float* __restrict__ x,
    const float* __restrict__ lnw, const float* __restrict__ lnb,
    const float* __restrict__ Gt, const double* __restrict__ csq_d,
    const unsigned int* __restrict__ cnt, const int* __restrict__ candI,
    const float* __restrict__ candS, int* __restrict__ out) {
  __shared__ float xs[4][DDIM];
  const int wave = threadIdx.x >> 6;
  const int lane = threadIdx.x & 63;
  const int row = blockIdx.x * 4 + wave;

  const float4* xr = (const float4*)(x + (size_t)row * DDIM);
  float4 v0 = xr[2*lane], v1 = xr[2*lane+1];
  float s = v0.x + v0.y + v0.z + v0.w + v1.x + v1.y + v1.z + v1.w;
#pragma unroll
  for (int m = 1; m < 64; m <<= 1) s += __shfl_xor(s, m, 64);
  const float mu = s * (1.0f / DDIM);
  float a0 = v0.x - mu, a1 = v0.y - mu, a2 = v0.z - mu, a3 = v0.w - mu;
  float a4 = v1.x - mu, a5 = v1.y - mu, a6 = v1.z - mu, a7 = v1.w - mu;
  float q = a0*a0 + a1*a1 + a2*a2 + a3*a3 + a4*a4 + a5*a5 + a6*a6 + a7*a7;
#pragma unroll
  for (int m = 1; m < 64; m <<= 1) q += __shfl_xor(q, m, 64);
  const float inv = rsqrtf(q * (1.0f / DDIM) + LN_EPS);
  const float4* wr = (const float4*)lnw;
  const float4* br = (const float4*)lnb;
  float4 w0 = wr[2*lane], w1 = wr[2*lane+1];
  float4 b0 = br[2*lane], b1 = br[2*lane+1];
  const float y0 = a0*inv*w0.x + b0.x, y1 = a1*inv*w0.y + b0.y;
  const float y2 = a2*inv*w0.z + b0.z, y3 = a3*inv*w0.w + b0.w;
  const float y4 = a4*inv*w1.x + b1.x, y5 = a5*inv*w1.y + b1.y;
  const float y6 = a6*inv*w1.z + b1.z, y7 = a7*inv*w1.w + b1.w;
  ((float4*)xs[wave])[2*lane]   = make_float4(y0, y1, y2, y3);
  ((float4*)xs[wave])[2*lane+1] = make_float4(y4, y5, y6, y7);

  const unsigned int count = cnt[row];
  double bs = 1e300;
  int bi = 0x7FFFFFFF;
  if (count <= CAND_MAX) {
    // lane i holds candidate i; filter by stored approximate score
    float si = 1e30f;
    int   ci = 0x7FFFFFFF;
    if (lane < (int)count) {
      si = candS[(size_t)row * CAND_MAX + lane];
      ci = candI[(size_t)row * CAND_MAX + lane];
    }
    float bsbf = si;
#pragma unroll
    for (int m = 1; m < 64; m <<= 1) bsbf = fminf(bsbf, __shfl_xor(bsbf, m, 64));
    unsigned long long mask = __ballot(si <= bsbf + RESCORE_WIN);
    while (mask) {
      const int l = __ffsll((long long)mask) - 1;
      mask &= mask - 1;
      const int n = __shfl(ci, l, 64);
      const float4* gr = (const float4*)(Gt + (size_t)n * DDIM);
      float4 g0 = gr[2*lane], g1 = gr[2*lane+1];
      float p = y0*g0.x;
      p = fmaf(y1, g0.y, p); p = fmaf(y2, g0.z, p); p = fmaf(y3, g0.w, p);
      p = fmaf(y4, g1.x, p); p = fmaf(y5, g1.y, p); p = fmaf(y6, g1.z, p);
      p = fmaf(y7, g1.w, p);
#pragma unroll
      for (int m = 1; m < 64; m <<= 1) p += __shfl_xor(p, m, 64);
      double sc = csq_d[n] - 2.0 * (double)p;
      if (sc < bs || (sc == bs && n < bi)) { bs = sc; bi = n; }
    }
    if (lane == 0) out[row] = bi;
  } else {
    // overflow: exact scan of all columns for this row (rare)
    for (int n = lane; n < CDIM; n += 64) {
      const float* g = Gt + (size_t)n * DDIM;
      float p = 0.f;
      for (int d = 0; d < DDIM; ++d) p = fmaf(xs[wave][d], g[d], p);
      double sc = csq_d[n] - 2.0 * (double)p;
      if (sc < bs || (sc == bs && n < bi)) { bs = sc; bi = n; }
    }
#pragma unroll
    for (int m = 1; m < 64; m <<= 1) {
      double os = __shfl_xor(bs, m, 64);
      int oi = __shfl_xor(bi, m, 64);
      if (os < bs || (os == bs && oi < bi)) { bs = os; bi = oi; }
    }
    if (lane == 0) out[row] = bi;
  }
}

extern "C" void kernel_launch(void* const* d_in, const int* in_sizes, int n_in,
                              void* d_out, int out_size, void* d_ws, size_t ws_size,
                              hipStream_t stream) {
  const float* x   = (const float*)d_in[0];
  const float* lnw = (const float*)d_in[1];
  const float* lnb = (const float*)d_in[2];
  const float* W   = (const float*)d_in[3];
  const float* cb  = (const float*)d_in[4];
  int* out = (int*)d_out;

  char* ws = (char*)d_ws;
  size_t off = 0;
  __hip_bfloat16* xb  = (__hip_bfloat16*)(ws + off); off += (size_t)MROWS * DDIM * 2;     // 16MB
  float*          Gt  = (float*)(ws + off);          off += (size_t)CDIM * DDIM * 4;      // 16MB
  __hip_bfloat16* Gtb = (__hip_bfloat16*)(ws + off); off += (size_t)CDIM * DDIM * 2;      // 8MB
  float*          csqf= (float*)(ws + off);          off += (size_t)CDIM * 4;
  double*         csqd= (double*)(ws + off);         off += (size_t)CDIM * 8;
  unsigned int*   cnt = (unsigned int*)(ws + off);   off += (size_t)MROWS * 4;
  unsigned int*   rmin= (unsigned int*)(ws + off);   off += (size_t)MROWS * 4;
  int*            candI=(int*)(ws + off);            off += (size_t)MROWS * CAND_MAX * 4; // 4MB
  float*          candS=(float*)(ws + off);          off += (size_t)MROWS * CAND_MAX * 4; // 4MB

  hipMemsetAsync(cnt, 0, (size_t)MROWS * 4, stream);
  hipMemsetAsync(rmin, 0xFF, (size_t)MROWS * 4, stream);
  k_ln<<<MROWS / 4, 256, 0, stream>>>(x, lnw, lnb, xb);
  k_csq<<<CDIM / 256, 256, 0, stream>>>(cb, csqf, csqd);
  k_gproj<<<dim3(CDIM / 128, DDIM / 128), dim3(16, 16), 0, stream>>>(W, cb, Gt, Gtb);
  k_score<<<(MROWS / 256) * (CDIM / 256), 512, 0, stream>>>(xb, Gtb, csqf, rmin, cnt, candI, candS);
  k_fixup<<<MROWS / 4, 256, 0, stream>>>(x, lnw, lnb, Gt, csqd, cnt, candI, candS, out);
}

// Round 5
// 408.860 us; speedup vs baseline: 1.0082x; 1.0082x over previous
//
#include <hip/hip_runtime.h>
#include <hip/hip_bf16.h>

#define MROWS 16384   // B*L
#define DDIM  512
#define HDIM  1024
#define CDIM  8192
#define LN_EPS 1e-5f
#define CAND_MAX 64
#define SCORE_DELTA 3.0f
#define RESCORE_WIN 3.0f

typedef __attribute__((ext_vector_type(8))) short bf16x8;
typedef __attribute__((ext_vector_type(4))) float f32x4;

__device__ __forceinline__ unsigned int f2key(float f) {
  unsigned int b = __float_as_uint(f);
  return (b & 0x80000000u) ? ~b : (b | 0x80000000u);
}
__device__ __forceinline__ float key2f(unsigned int k) {
  unsigned int b = (k & 0x80000000u) ? (k ^ 0x80000000u) : ~k;
  return __uint_as_float(b);
}

// -------- LayerNorm -> bf16 (one wave per row, 4 rows/block) + cnt/rmin init --
__global__ __launch_bounds__(256) void k_ln(const float* __restrict__ x,
                                            const float* __restrict__ lnw,
                                            const float* __restrict__ lnb,
                                            __hip_bfloat16* __restrict__ xb,
                                            unsigned int* __restrict__ cnt,
                                            unsigned int* __restrict__ rmin) {
  const int row = blockIdx.x * 4 + (threadIdx.x >> 6);
  const int t = threadIdx.x & 63;
  if (threadIdx.x < 4) {
    const int g = blockIdx.x * 4 + threadIdx.x;
    cnt[g] = 0u;
    rmin[g] = 0xFFFFFFFFu;
  }
  const float4* xr = (const float4*)(x + (size_t)row * DDIM);
  float4 v0 = xr[2 * t + 0];
  float4 v1 = xr[2 * t + 1];
  float s = v0.x + v0.y + v0.z + v0.w + v1.x + v1.y + v1.z + v1.w;
#pragma unroll
  for (int m = 1; m < 64; m <<= 1) s += __shfl_xor(s, m, 64);
  const float mu = s * (1.0f / DDIM);
  float a0 = v0.x - mu, a1 = v0.y - mu, a2 = v0.z - mu, a3 = v0.w - mu;
  float a4 = v1.x - mu, a5 = v1.y - mu, a6 = v1.z - mu, a7 = v1.w - mu;
  float q = a0*a0 + a1*a1 + a2*a2 + a3*a3 + a4*a4 + a5*a5 + a6*a6 + a7*a7;
#pragma unroll
  for (int m = 1; m < 64; m <<= 1) q += __shfl_xor(q, m, 64);
  const float inv = rsqrtf(q * (1.0f / DDIM) + LN_EPS);
  const float4* wr = (const float4*)lnw;
  const float4* br = (const float4*)lnb;
  float4 w0 = wr[2*t+0], w1 = wr[2*t+1];
  float4 b0 = br[2*t+0], b1 = br[2*t+1];
  float y[8];
  y[0] = a0*inv*w0.x + b0.x;  y[1] = a1*inv*w0.y + b0.y;
  y[2] = a2*inv*w0.z + b0.z;  y[3] = a3*inv*w0.w + b0.w;
  y[4] = a4*inv*w1.x + b1.x;  y[5] = a5*inv*w1.y + b1.y;
  y[6] = a6*inv*w1.z + b1.z;  y[7] = a7*inv*w1.w + b1.w;
  union { unsigned short u[8]; uint4 v4; } o;
#pragma unroll
  for (int i = 0; i < 8; ++i) {
    union { __hip_bfloat16 h; unsigned short us; } cv;
    cv.h = __float2bfloat16(y[i]);
    o.u[i] = cv.us;
  }
  *(uint4*)(xb + (size_t)row * DDIM + 8 * t) = o.v4;
}

// ---------------- c_sq[c] = sum_h cb[h][c]^2 (fp64 accumulate) ----------------
__global__ __launch_bounds__(256) void k_csq(const float* __restrict__ cb,
                                             float* __restrict__ csq_f,
                                             double* __restrict__ csq_d) {
  const int c = blockIdx.x * 256 + threadIdx.x;
  double a = 0.0;
  for (int h = 0; h < HDIM; ++h) {
    float v = cb[(size_t)h * CDIM + c];
    a += (double)v * (double)v;
  }
  csq_f[c] = (float)a;
  csq_d[c] = a;
}

// ------- Gt[n][d] = sum_h W[h][d]*cb[h][n] (fp32; 128x128 tile, 8x8/thread) ---
// Per-element accumulation order kept bit-identical across rounds.
__global__ __launch_bounds__(256) void k_gproj(const float* __restrict__ W,
                                               const float* __restrict__ cb,
                                               float* __restrict__ Gt,
                                               __hip_bfloat16* __restrict__ Gtb) {
  __shared__ float Ws[32][128];   // [h][d]
  __shared__ float Cs[32][128];   // [h][n]
  const int tx = threadIdx.x;     // 16, d-sub
  const int ty = threadIdx.y;     // 16, n-sub
  const int n0 = blockIdx.x * 128;
  const int d0 = blockIdx.y * 128;
  const int lin = ty * 16 + tx;
  float accm[8][8];               // [n][d]
#pragma unroll
  for (int j = 0; j < 8; ++j)
#pragma unroll
    for (int i = 0; i < 8; ++i) accm[j][i] = 0.0f;

  for (int h0 = 0; h0 < HDIM; h0 += 32) {
    __syncthreads();
#pragma unroll
    for (int i = 0; i < 4; ++i) {
      int f = lin + 256 * i;
      int hh = f >> 5, e4 = f & 31;
      ((float4*)&Ws[hh][0])[e4] = ((const float4*)(W  + (size_t)(h0 + hh) * DDIM + d0))[e4];
      ((float4*)&Cs[hh][0])[e4] = ((const float4*)(cb + (size_t)(h0 + hh) * CDIM + n0))[e4];
    }
    __syncthreads();
    float accs[8][8];
#pragma unroll
    for (int j = 0; j < 8; ++j)
#pragma unroll
      for (int i = 0; i < 8; ++i) accs[j][i] = 0.0f;
#pragma unroll
    for (int k = 0; k < 32; ++k) {
      float4 av0 = ((const float4*)&Ws[k][0])[tx];
      float4 av1 = ((const float4*)&Ws[k][0])[tx + 16];
      float4 bv0 = ((const float4*)&Cs[k][0])[ty];
      float4 bv1 = ((const float4*)&Cs[k][0])[ty + 16];
      float aa[8] = {av0.x, av0.y, av0.z, av0.w, av1.x, av1.y, av1.z, av1.w};
      float bb[8] = {bv0.x, bv0.y, bv0.z, bv0.w, bv1.x, bv1.y, bv1.z, bv1.w};
#pragma unroll
      for (int j = 0; j < 8; ++j)
#pragma unroll
        for (int i = 0; i < 8; ++i) accs[j][i] = fmaf(bb[j], aa[i], accs[j][i]);
    }
#pragma unroll
    for (int j = 0; j < 8; ++j)
#pragma unroll
      for (int i = 0; i < 8; ++i) accm[j][i] += accs[j][i];
  }
#pragma unroll
  for (int j = 0; j < 8; ++j) {
    const int n = n0 + ty * 4 + (j >> 2) * 64 + (j & 3);
#pragma unroll
    for (int di = 0; di < 2; ++di) {
      float4 o = make_float4(accm[j][di*4+0], accm[j][di*4+1], accm[j][di*4+2], accm[j][di*4+3]);
      ((float4*)(Gt + (size_t)n * DDIM + d0))[tx + di * 16] = o;
      union { __hip_bfloat16 h; unsigned short us; } c0, c1, c2, c3;
      c0.h = __float2bfloat16(o.x); c1.h = __float2bfloat16(o.y);
      c2.h = __float2bfloat16(o.z); c3.h = __float2bfloat16(o.w);
      ((ushort4*)(Gtb + (size_t)n * DDIM + d0))[tx + di * 16] = make_ushort4(c0.us, c1.us, c2.us, c3.us);
    }
  }
}

// ========== 256x256 MFMA scoring: BK=32, 4-buffer ring, depth-3 prefetch ======
// Ring slot (T&3) = 32 KB: A [256 rows][32 k] bf16 at +0, B [256 n][32 k] at
// +16384. Rows are 64 B = 4x16B slots; phys slot = logical ^ ((row>>1)&3)
// (zero-conflict b128 reads, verified R4). gload_lds dest linear; inverse
// swizzle on the global source slot (sce). Issue K-tile T+3 while computing T:
// waits reference loads aged 3 K-tiles -> vmcnt(12) always satisfied in
// steady state; tail counts down 8/4/0. Two barriers/iter:
//  top:  STAGE(T+3) [slot free since T-1's end barrier]; vmcnt; barrier
//  then: ds_read frags(T) + 32 MFMA; barrier [fences T's reads from T+4's stage]

#define GLL(SRC, DST) __builtin_amdgcn_global_load_lds( \
    (const __attribute__((address_space(1))) unsigned int*)(SRC), \
    (__attribute__((address_space(3))) unsigned int*)(DST), 16, 0, 0)

#define STAGE32(KT) { \
  const int rb_ = ((KT) & 3) * 32768; \
  GLL(gA + (size_t)sr0 * 512 + ((KT)*32 + sce*8), lds + rb_ +         t*16); \
  GLL(gA + (size_t)sr1 * 512 + ((KT)*32 + sce*8), lds + rb_ +  8192 + t*16); \
  GLL(gB + (size_t)sr0 * 512 + ((KT)*32 + sce*8), lds + rb_ + 16384 + t*16); \
  GLL(gB + (size_t)sr1 * 512 + ((KT)*32 + sce*8), lds + rb_ + 24576 + t*16); }

#define KITER(T, DOSTAGE, WAITSTR) do { \
  if (DOSTAGE) STAGE32((T) + 3); \
  asm volatile("s_waitcnt " WAITSTR ::: "memory"); \
  __builtin_amdgcn_s_barrier(); \
  __builtin_amdgcn_sched_barrier(0); \
  { \
    const char* Ab_ = lds + ((T) & 3) * 32768; \
    const char* Bb_ = Ab_ + 16384; \
    bf16x8 b[4]; \
    _Pragma("unroll") for (int ni_ = 0; ni_ < 4; ++ni_) \
      b[ni_] = *(const bf16x8*)(Bb_ + boffb + ni_ * 1024); \
    _Pragma("unroll") for (int mh_ = 0; mh_ < 2; ++mh_) { \
      bf16x8 a[4]; \
      _Pragma("unroll") for (int mi_ = 0; mi_ < 4; ++mi_) \
        a[mi_] = *(const bf16x8*)(Ab_ + aoffb + (mh_ * 4 + mi_) * 1024); \
      __builtin_amdgcn_s_setprio(1); \
      _Pragma("unroll") for (int mi_ = 0; mi_ < 4; ++mi_) \
      _Pragma("unroll") for (int ni_ = 0; ni_ < 4; ++ni_) \
        acc[mh_*4+mi_][ni_] = __builtin_amdgcn_mfma_f32_16x16x32_bf16(a[mi_], b[ni_], acc[mh_*4+mi_][ni_], 0, 0, 0); \
      __builtin_amdgcn_s_setprio(0); \
    } \
  } \
  __builtin_amdgcn_sched_barrier(0); \
  __builtin_amdgcn_s_barrier(); \
} while (0)

__global__ __launch_bounds__(512, 2) void k_score(
    const __hip_bfloat16* __restrict__ xb,   // [16384][512]
    const __hip_bfloat16* __restrict__ Gtb,  // [8192][512]
    const float* __restrict__ csq,           // [8192]
    unsigned int* __restrict__ rowminG,      // [16384] key-encoded, init 0xFF
    unsigned int* __restrict__ cnt,          // [16384]
    int* __restrict__ candI,                 // [16384][CAND_MAX]
    float* __restrict__ candS)               // [16384][CAND_MAX]
{
  __shared__ __align__(16) char lds[131072];
  __shared__ unsigned int rowthr[256];

  const int t = threadIdx.x;
  const int wave = t >> 6;
  const int lane = t & 63;
  const int l15 = lane & 15;
  const int l4  = lane >> 4;
  const int wm = wave >> 2;   // 2 waves in M
  const int wn = wave & 3;    // 4 waves in N

  // n-major block order + bijective XCD-chunked swizzle (2048 % 8 == 0)
  const int bid = blockIdx.x;
  const int sbid = (bid & 7) * 256 + (bid >> 3);
  const int n_blk = sbid >> 6;   // 0..31
  const int m_blk = sbid & 63;   // 0..63
  const int rowbase = m_blk * 256;
  const int colbase = n_blk * 256;

  const unsigned short* gA = (const unsigned short*)xb  + (size_t)rowbase * 512;
  const unsigned short* gB = (const unsigned short*)Gtb + (size_t)colbase * 512;

  const int sr0 = t >> 2;
  const int sr1 = sr0 + 128;
  const int sce = (t & 3) ^ ((t >> 3) & 3);   // inverse-swizzled global slot

  if (t < 256) rowthr[t] = 0xFFFFFFFFu;

  const int swz = ((l4 ^ ((l15 >> 1) & 3)) << 4);
  const int aoffb = (wm * 128 + l15) * 64 + swz;
  const int boffb = (wn * 64  + l15) * 64 + swz;

  f32x4 acc[8][4];
#pragma unroll
  for (int i = 0; i < 8; ++i)
#pragma unroll
    for (int j = 0; j < 4; ++j) acc[i][j] = (f32x4){0.f, 0.f, 0.f, 0.f};

  // ---- prologue: stage K-tiles 0,1,2 (12 loads in flight) ----
  STAGE32(0);
  STAGE32(1);
  STAGE32(2);

  // ---- 16 K-tiles; stage T+3 during T; never drain below 12 until tail ----
  KITER( 0, 1, "vmcnt(12)");
  KITER( 1, 1, "vmcnt(12)");
  KITER( 2, 1, "vmcnt(12)");
  KITER( 3, 1, "vmcnt(12)");
  KITER( 4, 1, "vmcnt(12)");
  KITER( 5, 1, "vmcnt(12)");
  KITER( 6, 1, "vmcnt(12)");
  KITER( 7, 1, "vmcnt(12)");
  KITER( 8, 1, "vmcnt(12)");
  KITER( 9, 1, "vmcnt(12)");
  KITER(10, 1, "vmcnt(12)");
  KITER(11, 1, "vmcnt(12)");
  KITER(12, 1, "vmcnt(12)");
  KITER(13, 0, "vmcnt(8)");
  KITER(14, 0, "vmcnt(4)");
  KITER(15, 0, "vmcnt(0)");

  // ---- epilogue: s = csq - 2*dot ; block/global running min ; capture ----
  float csqv[4];
#pragma unroll
  for (int ni = 0; ni < 4; ++ni) csqv[ni] = csq[colbase + wn*64 + ni*16 + l15];

#pragma unroll
  for (int mi = 0; mi < 8; ++mi) {
#pragma unroll
    for (int r = 0; r < 4; ++r) {
      float mn = 1e30f;
#pragma unroll
      for (int ni = 0; ni < 4; ++ni) mn = fminf(mn, fmaf(-2.0f, acc[mi][ni][r], csqv[ni]));
#pragma unroll
      for (int msk = 1; msk < 16; msk <<= 1) mn = fminf(mn, __shfl_xor(mn, msk, 64));
      if (l15 == 0) {
        const int rowl = wm*128 + mi*16 + l4*4 + r;
        atomicMin(&rowthr[rowl], f2key(mn));
      }
    }
  }
  __syncthreads();
  if (t < 256) {
    unsigned int lk = rowthr[t];
    unsigned int old = atomicMin(&rowminG[rowbase + t], lk);
    if (old < lk) atomicMin(&rowthr[t], old);
  }
  __syncthreads();
#pragma unroll
  for (int mi = 0; mi < 8; ++mi) {
#pragma unroll
    for (int r = 0; r < 4; ++r) {
      const int rowl = wm*128 + mi*16 + l4*4 + r;
      const float thr = key2f(rowthr[rowl]) + SCORE_DELTA;
#pragma unroll
      for (int ni = 0; ni < 4; ++ni) {
        float sv = fmaf(-2.0f, acc[mi][ni][r], csqv[ni]);
        if (sv <= thr) {
          const int grow = rowbase + rowl;
          unsigned int old = atomicAdd(&cnt[grow], 1u);
          if (old < CAND_MAX) {
            candI[(size_t)grow * CAND_MAX + old] = colbase + wn*64 + ni*16 + l15;
            candS[(size_t)grow * CAND_MAX + old] = sv;
          }
        }
      }
    }
  }
}

// ------- exact fp32/fp64 rescore, filtered by stored bf16-MFMA scores --------
__global__ __launch_bounds__(256) void k_fixup(const float* __restrict__ x,
    const float* __restrict__ lnw, const float* __restrict__ lnb,
    const float* __restrict__ Gt, const double* __restrict__ csq_d,
    const unsigned int* __restrict__ cnt, const int* __restrict__ candI,
    const float* __restrict__ candS, int* __restrict__ out) {
  __shared__ float xs[4][DDIM];
  const int wave = threadIdx.x >> 6;
  const int lane = threadIdx.x & 63;
  const int row = blockIdx.x * 4 + wave;

  const float4* xr = (const float4*)(x + (size_t)row * DDIM);
  float4 v0 = xr[2*lane], v1 = xr[2*lane+1];
  float s = v0.x + v0.y + v0.z + v0.w + v1.x + v1.y + v1.z + v1.w;
#pragma unroll
  for (int m = 1; m < 64; m <<= 1) s += __shfl_xor(s, m, 64);
  const float mu = s * (1.0f / DDIM);
  float a0 = v0.x - mu, a1 = v0.y - mu, a2 = v0.z - mu, a3 = v0.w - mu;
  float a4 = v1.x - mu, a5 = v1.y - mu, a6 = v1.z - mu, a7 = v1.w - mu;
  float q = a0*a0 + a1*a1 + a2*a2 + a3*a3 + a4*a4 + a5*a5 + a6*a6 + a7*a7;
#pragma unroll
  for (int m = 1; m < 64; m <<= 1) q += __shfl_xor(q, m, 64);
  const float inv = rsqrtf(q * (1.0f / DDIM) + LN_EPS);
  const float4* wr = (const float4*)lnw;
  const float4* br = (const float4*)lnb;
  float4 w0 = wr[2*lane], w1 = wr[2*lane+1];
  float4 b0 = br[2*lane], b1 = br[2*lane+1];
  const float y0 = a0*inv*w0.x + b0.x, y1 = a1*inv*w0.y + b0.y;
  const float y2 = a2*inv*w0.z + b0.z, y3 = a3*inv*w0.w + b0.w;
  const float y4 = a4*inv*w1.x + b1.x, y5 = a5*inv*w1.y + b1.y;
  const float y6 = a6*inv*w1.z + b1.z, y7 = a7*inv*w1.w + b1.w;
  ((float4*)xs[wave])[2*lane]   = make_float4(y0, y1, y2, y3);
  ((float4*)xs[wave])[2*lane+1] = make_float4(y4, y5, y6, y7);

  const unsigned int count = cnt[row];
  double bs = 1e300;
  int bi = 0x7FFFFFFF;
  if (count <= CAND_MAX) {
    // lane i holds candidate i; filter by stored approximate score
    float si = 1e30f;
    int   ci = 0x7FFFFFFF;
    if (lane < (int)count) {
      si = candS[(size_t)row * CAND_MAX + lane];
      ci = candI[(size_t)row * CAND_MAX + lane];
    }
    float bsbf = si;
#pragma unroll
    for (int m = 1; m < 64; m <<= 1) bsbf = fminf(bsbf, __shfl_xor(bsbf, m, 64));
    unsigned long long mask = __ballot(si <= bsbf + RESCORE_WIN);
    while (mask) {
      const int l = __ffsll((long long)mask) - 1;
      mask &= mask - 1;
      const int n = __shfl(ci, l, 64);
      const float4* gr = (const float4*)(Gt + (size_t)n * DDIM);
      float4 g0 = gr[2*lane], g1 = gr[2*lane+1];
      float p = y0*g0.x;
      p = fmaf(y1, g0.y, p); p = fmaf(y2, g0.z, p); p = fmaf(y3, g0.w, p);
      p = fmaf(y4, g1.x, p); p = fmaf(y5, g1.y, p); p = fmaf(y6, g1.z, p);
      p = fmaf(y7, g1.w, p);
#pragma unroll
      for (int m = 1; m < 64; m <<= 1) p += __shfl_xor(p, m, 64);
      double sc = csq_d[n] - 2.0 * (double)p;
      if (sc < bs || (sc == bs && n < bi)) { bs = sc; bi = n; }
    }
    if (lane == 0) out[row] = bi;
  } else {
    // overflow: exact scan of all columns for this row (rare)
    for (int n = lane; n < CDIM; n += 64) {
      const float* g = Gt + (size_t)n * DDIM;
      float p = 0.f;
      for (int d = 0; d < DDIM; ++d) p = fmaf(xs[wave][d], g[d], p);
      double sc = csq_d[n] - 2.0 * (double)p;
      if (sc < bs || (sc == bs && n < bi)) { bs = sc; bi = n; }
    }
#pragma unroll
    for (int m = 1; m < 64; m <<= 1) {
      double os = __shfl_xor(bs, m, 64);
      int oi = __shfl_xor(bi, m, 64);
      if (os < bs || (os == bs && oi < bi)) { bs = os; bi = oi; }
    }
    if (lane == 0) out[row] = bi;
  }
}

extern "C" void kernel_launch(void* const* d_in, const int* in_sizes, int n_in,
                              void* d_out, int out_size, void* d_ws, size_t ws_size,
                              hipStream_t stream) {
  const float* x   = (const float*)d_in[0];
  const float* lnw = (const float*)d_in[1];
  const float* lnb = (const float*)d_in[2];
  const float* W   = (const float*)d_in[3];
  const float* cb  = (const float*)d_in[4];
  int* out = (int*)d_out;

  char* ws = (char*)d_ws;
  size_t off = 0;
  __hip_bfloat16* xb  = (__hip_bfloat16*)(ws + off); off += (size_t)MROWS * DDIM * 2;     // 16MB
  float*          Gt  = (float*)(ws + off);          off += (size_t)CDIM * DDIM * 4;      // 16MB
  __hip_bfloat16* Gtb = (__hip_bfloat16*)(ws + off); off += (size_t)CDIM * DDIM * 2;      // 8MB
  float*          csqf= (float*)(ws + off);          off += (size_t)CDIM * 4;
  double*         csqd= (double*)(ws + off);         off += (size_t)CDIM * 8;
  unsigned int*   cnt = (unsigned int*)(ws + off);   off += (size_t)MROWS * 4;
  unsigned int*   rmin= (unsigned int*)(ws + off);   off += (size_t)MROWS * 4;
  int*            candI=(int*)(ws + off);            off += (size_t)MROWS * CAND_MAX * 4; // 4MB
  float*          candS=(float*)(ws + off);          off += (size_t)MROWS * CAND_MAX * 4; // 4MB

  k_ln<<<MROWS / 4, 256, 0, stream>>>(x, lnw, lnb, xb, cnt, rmin);
  k_csq<<<CDIM / 256, 256, 0, stream>>>(cb, csqf, csqd);
  k_gproj<<<dim3(CDIM / 128, DDIM / 128), dim3(16, 16), 0, stream>>>(W, cb, Gt, Gtb);
  k_score<<<(MROWS / 256) * (CDIM / 256), 512, 0, stream>>>(xb, Gtb, csqf, rmin, cnt, candI, candS);
  k_fixup<<<MROWS / 4, 256, 0, stream>>>(x, lnw, lnb, Gt, csqd, cnt, candI, candS, out);
}

// Round 6
// 369.316 us; speedup vs baseline: 1.1162x; 1.1071x over previous
//
#include <hip/hip_runtime.h>
#include <hip/hip_bf16.h>

#define MROWS 16384   // B*L
#define DDIM  512
#define HDIM  1024
#define CDIM  8192
#define LN_EPS 1e-5f
#define CAND_MAX 64
#define SCORE_DELTA 3.0f
#define RESCORE_WIN 3.0f

typedef __attribute__((ext_vector_type(8))) short bf16x8;
typedef __attribute__((ext_vector_type(4))) float f32x4;

__device__ __forceinline__ unsigned int f2key(float f) {
  unsigned int b = __float_as_uint(f);
  return (b & 0x80000000u) ? ~b : (b | 0x80000000u);
}
__device__ __forceinline__ float key2f(unsigned int k) {
  unsigned int b = (k & 0x80000000u) ? (k ^ 0x80000000u) : ~k;
  return __uint_as_float(b);
}

// -------- LayerNorm -> bf16 (one wave per row, 4 rows/block) + cnt/rmin init --
__global__ __launch_bounds__(256) void k_ln(const float* __restrict__ x,
                                            const float* __restrict__ lnw,
                                            const float* __restrict__ lnb,
                                            __hip_bfloat16* __restrict__ xb,
                                            unsigned int* __restrict__ cnt,
                                            unsigned int* __restrict__ rmin) {
  const int row = blockIdx.x * 4 + (threadIdx.x >> 6);
  const int t = threadIdx.x & 63;
  if (threadIdx.x < 4) {
    const int g = blockIdx.x * 4 + threadIdx.x;
    cnt[g] = 0u;
    rmin[g] = 0xFFFFFFFFu;
  }
  const float4* xr = (const float4*)(x + (size_t)row * DDIM);
  float4 v0 = xr[2 * t + 0];
  float4 v1 = xr[2 * t + 1];
  float s = v0.x + v0.y + v0.z + v0.w + v1.x + v1.y + v1.z + v1.w;
#pragma unroll
  for (int m = 1; m < 64; m <<= 1) s += __shfl_xor(s, m, 64);
  const float mu = s * (1.0f / DDIM);
  float a0 = v0.x - mu, a1 = v0.y - mu, a2 = v0.z - mu, a3 = v0.w - mu;
  float a4 = v1.x - mu, a5 = v1.y - mu, a6 = v1.z - mu, a7 = v1.w - mu;
  float q = a0*a0 + a1*a1 + a2*a2 + a3*a3 + a4*a4 + a5*a5 + a6*a6 + a7*a7;
#pragma unroll
  for (int m = 1; m < 64; m <<= 1) q += __shfl_xor(q, m, 64);
  const float inv = rsqrtf(q * (1.0f / DDIM) + LN_EPS);
  const float4* wr = (const float4*)lnw;
  const float4* br = (const float4*)lnb;
  float4 w0 = wr[2*t+0], w1 = wr[2*t+1];
  float4 b0 = br[2*t+0], b1 = br[2*t+1];
  float y[8];
  y[0] = a0*inv*w0.x + b0.x;  y[1] = a1*inv*w0.y + b0.y;
  y[2] = a2*inv*w0.z + b0.z;  y[3] = a3*inv*w0.w + b0.w;
  y[4] = a4*inv*w1.x + b1.x;  y[5] = a5*inv*w1.y + b1.y;
  y[6] = a6*inv*w1.z + b1.z;  y[7] = a7*inv*w1.w + b1.w;
  union { unsigned short u[8]; uint4 v4; } o;
#pragma unroll
  for (int i = 0; i < 8; ++i) {
    union { __hip_bfloat16 h; unsigned short us; } cv;
    cv.h = __float2bfloat16(y[i]);
    o.u[i] = cv.us;
  }
  *(uint4*)(xb + (size_t)row * DDIM + 8 * t) = o.v4;
}

// ---------------- c_sq[c] = sum_h cb[h][c]^2 (fp64 accumulate) ----------------
__global__ __launch_bounds__(256) void k_csq(const float* __restrict__ cb,
                                             float* __restrict__ csq_f,
                                             double* __restrict__ csq_d) {
  const int c = blockIdx.x * 256 + threadIdx.x;
  double a = 0.0;
  for (int h = 0; h < HDIM; ++h) {
    float v = cb[(size_t)h * CDIM + c];
    a += (double)v * (double)v;
  }
  csq_f[c] = (float)a;
  csq_d[c] = a;
}

// ------- Gt[n][d] = sum_h W[h][d]*cb[h][n] (fp32; 128x128 tile, 8x8/thread) ---
// Per-element accumulation order kept bit-identical across rounds.
__global__ __launch_bounds__(256) void k_gproj(const float* __restrict__ W,
                                               const float* __restrict__ cb,
                                               float* __restrict__ Gt,
                                               __hip_bfloat16* __restrict__ Gtb) {
  __shared__ float Ws[32][128];   // [h][d]
  __shared__ float Cs[32][128];   // [h][n]
  const int tx = threadIdx.x;     // 16, d-sub
  const int ty = threadIdx.y;     // 16, n-sub
  const int n0 = blockIdx.x * 128;
  const int d0 = blockIdx.y * 128;
  const int lin = ty * 16 + tx;
  float accm[8][8];               // [n][d]
#pragma unroll
  for (int j = 0; j < 8; ++j)
#pragma unroll
    for (int i = 0; i < 8; ++i) accm[j][i] = 0.0f;

  for (int h0 = 0; h0 < HDIM; h0 += 32) {
    __syncthreads();
#pragma unroll
    for (int i = 0; i < 4; ++i) {
      int f = lin + 256 * i;
      int hh = f >> 5, e4 = f & 31;
      ((float4*)&Ws[hh][0])[e4] = ((const float4*)(W  + (size_t)(h0 + hh) * DDIM + d0))[e4];
      ((float4*)&Cs[hh][0])[e4] = ((const float4*)(cb + (size_t)(h0 + hh) * CDIM + n0))[e4];
    }
    __syncthreads();
    float accs[8][8];
#pragma unroll
    for (int j = 0; j < 8; ++j)
#pragma unroll
      for (int i = 0; i < 8; ++i) accs[j][i] = 0.0f;
#pragma unroll
    for (int k = 0; k < 32; ++k) {
      float4 av0 = ((const float4*)&Ws[k][0])[tx];
      float4 av1 = ((const float4*)&Ws[k][0])[tx + 16];
      float4 bv0 = ((const float4*)&Cs[k][0])[ty];
      float4 bv1 = ((const float4*)&Cs[k][0])[ty + 16];
      float aa[8] = {av0.x, av0.y, av0.z, av0.w, av1.x, av1.y, av1.z, av1.w};
      float bb[8] = {bv0.x, bv0.y, bv0.z, bv0.w, bv1.x, bv1.y, bv1.z, bv1.w};
#pragma unroll
      for (int j = 0; j < 8; ++j)
#pragma unroll
        for (int i = 0; i < 8; ++i) accs[j][i] = fmaf(bb[j], aa[i], accs[j][i]);
    }
#pragma unroll
    for (int j = 0; j < 8; ++j)
#pragma unroll
      for (int i = 0; i < 8; ++i) accm[j][i] += accs[j][i];
  }
#pragma unroll
  for (int j = 0; j < 8; ++j) {
    const int n = n0 + ty * 4 + (j >> 2) * 64 + (j & 3);
#pragma unroll
    for (int di = 0; di < 2; ++di) {
      float4 o = make_float4(accm[j][di*4+0], accm[j][di*4+1], accm[j][di*4+2], accm[j][di*4+3]);
      ((float4*)(Gt + (size_t)n * DDIM + d0))[tx + di * 16] = o;
      union { __hip_bfloat16 h; unsigned short us; } c0, c1, c2, c3;
      c0.h = __float2bfloat16(o.x); c1.h = __float2bfloat16(o.y);
      c2.h = __float2bfloat16(o.z); c3.h = __float2bfloat16(o.w);
      ((ushort4*)(Gtb + (size_t)n * DDIM + d0))[tx + di * 16] = make_ushort4(c0.us, c1.us, c2.us, c3.us);
    }
  }
}

// ====== 128x256 MFMA scoring: BK=32, double-buffer, 2 blocks/CU (TLP) ========
// Per-wave output 64x64 -> acc[4][4] = 64 VGPR; __launch_bounds__(512,4)
// forces total regs <= 128 -> 4 waves/SIMD (2 blocks/CU). LDS/slot = 24 KB:
// A [128 rows][32 k] bf16 at +0, B [256 n][32 k] at +8192; 2 slots = 48 KB.
// Rows are 64 B = 4x16B slots; phys slot = logical ^ ((row>>1)&3) (zero-
// conflict b128 reads, verified R4/R5). gload_lds dest linear; inverse
// swizzle on global source slot (sce; also valid for B's +128 rows since
// 128 = 0 mod 4). Stage T+1 while computing T; vmcnt(3) waits loads one
// full iter old; the co-resident block fills any residual stall.

#define GLL(SRC, DST) __builtin_amdgcn_global_load_lds( \
    (const __attribute__((address_space(1))) unsigned int*)(SRC), \
    (__attribute__((address_space(3))) unsigned int*)(DST), 16, 0, 0)

#define STAGE24(KT) { \
  const int rb_ = ((KT) & 1) * 24576; \
  GLL(gA + (size_t)sr0 * 512 + ((KT)*32 + sce*8), lds + rb_ +         t*16); \
  GLL(gB + (size_t)sr0 * 512 + ((KT)*32 + sce*8), lds + rb_ +  8192 + t*16); \
  GLL(gB + (size_t)(sr0 + 128) * 512 + ((KT)*32 + sce*8), lds + rb_ + 16384 + t*16); }

#define KITER(T, DOSTAGE, WAITSTR) do { \
  if (DOSTAGE) STAGE24((T) + 1); \
  asm volatile("s_waitcnt " WAITSTR ::: "memory"); \
  __builtin_amdgcn_s_barrier(); \
  __builtin_amdgcn_sched_barrier(0); \
  { \
    const char* Sb_ = lds + ((T) & 1) * 24576; \
    bf16x8 a[4], b[4]; \
    _Pragma("unroll") for (int ni_ = 0; ni_ < 4; ++ni_) \
      b[ni_] = *(const bf16x8*)(Sb_ + 8192 + boffb + ni_ * 1024); \
    _Pragma("unroll") for (int mi_ = 0; mi_ < 4; ++mi_) \
      a[mi_] = *(const bf16x8*)(Sb_ + aoffb + mi_ * 1024); \
    __builtin_amdgcn_s_setprio(1); \
    _Pragma("unroll") for (int mi_ = 0; mi_ < 4; ++mi_) \
    _Pragma("unroll") for (int ni_ = 0; ni_ < 4; ++ni_) \
      acc[mi_][ni_] = __builtin_amdgcn_mfma_f32_16x16x32_bf16(a[mi_], b[ni_], acc[mi_][ni_], 0, 0, 0); \
    __builtin_amdgcn_s_setprio(0); \
  } \
  __builtin_amdgcn_sched_barrier(0); \
  __builtin_amdgcn_s_barrier(); \
} while (0)

__global__ __launch_bounds__(512, 4) void k_score(
    const __hip_bfloat16* __restrict__ xb,   // [16384][512]
    const __hip_bfloat16* __restrict__ Gtb,  // [8192][512]
    const float* __restrict__ csq,           // [8192]
    unsigned int* __restrict__ rowminG,      // [16384] key-encoded, init 0xFF
    unsigned int* __restrict__ cnt,          // [16384]
    int* __restrict__ candI,                 // [16384][CAND_MAX]
    float* __restrict__ candS)               // [16384][CAND_MAX]
{
  __shared__ __align__(16) char lds[49152];
  __shared__ unsigned int rowthr[128];

  const int t = threadIdx.x;
  const int wave = t >> 6;
  const int lane = t & 63;
  const int l15 = lane & 15;
  const int l4  = lane >> 4;
  const int wm = wave >> 2;   // 2 waves in M (64 rows each)
  const int wn = wave & 3;    // 4 waves in N (64 cols each)

  // n-major block order + bijective XCD-chunked swizzle (4096 % 8 == 0)
  const int bid = blockIdx.x;
  const int sbid = (bid & 7) * 512 + (bid >> 3);
  const int n_blk = sbid >> 7;   // 0..31
  const int m_blk = sbid & 127;  // 0..127
  const int rowbase = m_blk * 128;
  const int colbase = n_blk * 256;

  const unsigned short* gA = (const unsigned short*)xb  + (size_t)rowbase * 512;
  const unsigned short* gB = (const unsigned short*)Gtb + (size_t)colbase * 512;

  const int sr0 = t >> 2;                     // 0..127
  const int sce = (t & 3) ^ ((t >> 3) & 3);   // inverse-swizzled global slot

  if (t < 128) rowthr[t] = 0xFFFFFFFFu;

  const int swz = ((l4 ^ ((l15 >> 1) & 3)) << 4);
  const int aoffb = (wm * 64 + l15) * 64 + swz;
  const int boffb = (wn * 64 + l15) * 64 + swz;

  f32x4 acc[4][4];
#pragma unroll
  for (int i = 0; i < 4; ++i)
#pragma unroll
    for (int j = 0; j < 4; ++j) acc[i][j] = (f32x4){0.f, 0.f, 0.f, 0.f};

  // ---- prologue: stage K-tile 0 ----
  STAGE24(0);

  // ---- 16 K-tiles; stage T+1 during T ----
  KITER( 0, 1, "vmcnt(3)");
  KITER( 1, 1, "vmcnt(3)");
  KITER( 2, 1, "vmcnt(3)");
  KITER( 3, 1, "vmcnt(3)");
  KITER( 4, 1, "vmcnt(3)");
  KITER( 5, 1, "vmcnt(3)");
  KITER( 6, 1, "vmcnt(3)");
  KITER( 7, 1, "vmcnt(3)");
  KITER( 8, 1, "vmcnt(3)");
  KITER( 9, 1, "vmcnt(3)");
  KITER(10, 1, "vmcnt(3)");
  KITER(11, 1, "vmcnt(3)");
  KITER(12, 1, "vmcnt(3)");
  KITER(13, 1, "vmcnt(3)");
  KITER(14, 1, "vmcnt(3)");
  KITER(15, 0, "vmcnt(0)");

  // ---- epilogue: s = csq - 2*dot ; block/global running min ; capture ----
  float csqv[4];
#pragma unroll
  for (int ni = 0; ni < 4; ++ni) csqv[ni] = csq[colbase + wn*64 + ni*16 + l15];

#pragma unroll
  for (int mi = 0; mi < 4; ++mi) {
#pragma unroll
    for (int r = 0; r < 4; ++r) {
      float mn = 1e30f;
#pragma unroll
      for (int ni = 0; ni < 4; ++ni) mn = fminf(mn, fmaf(-2.0f, acc[mi][ni][r], csqv[ni]));
#pragma unroll
      for (int msk = 1; msk < 16; msk <<= 1) mn = fminf(mn, __shfl_xor(mn, msk, 64));
      if (l15 == 0) {
        const int rowl = wm*64 + mi*16 + l4*4 + r;
        atomicMin(&rowthr[rowl], f2key(mn));
      }
    }
  }
  __syncthreads();
  if (t < 128) {
    unsigned int lk = rowthr[t];
    unsigned int old = atomicMin(&rowminG[rowbase + t], lk);
    if (old < lk) atomicMin(&rowthr[t], old);
  }
  __syncthreads();
#pragma unroll
  for (int mi = 0; mi < 4; ++mi) {
#pragma unroll
    for (int r = 0; r < 4; ++r) {
      const int rowl = wm*64 + mi*16 + l4*4 + r;
      const float thr = key2f(rowthr[rowl]) + SCORE_DELTA;
#pragma unroll
      for (int ni = 0; ni < 4; ++ni) {
        float sv = fmaf(-2.0f, acc[mi][ni][r], csqv[ni]);
        if (sv <= thr) {
          const int grow = rowbase + rowl;
          unsigned int old = atomicAdd(&cnt[grow], 1u);
          if (old < CAND_MAX) {
            candI[(size_t)grow * CAND_MAX + old] = colbase + wn*64 + ni*16 + l15;
            candS[(size_t)grow * CAND_MAX + old] = sv;
          }
        }
      }
    }
  }
}

// ------- exact fp32/fp64 rescore, filtered by stored bf16-MFMA scores --------
__global__ __launch_bounds__(256) void k_fixup(const float* __restrict__ x,
    const float* __restrict__ lnw, const float* __restrict__ lnb,
    const float* __restrict__ Gt, const double* __restrict__ csq_d,
    const unsigned int* __restrict__ cnt, const int* __restrict__ candI,
    const float* __restrict__ candS, int* __restrict__ out) {
  __shared__ float xs[4][DDIM];
  const int wave = threadIdx.x >> 6;
  const int lane = threadIdx.x & 63;
  const int row = blockIdx.x * 4 + wave;

  const float4* xr = (const float4*)(x + (size_t)row * DDIM);
  float4 v0 = xr[2*lane], v1 = xr[2*lane+1];
  float s = v0.x + v0.y + v0.z + v0.w + v1.x + v1.y + v1.z + v1.w;
#pragma unroll
  for (int m = 1; m < 64; m <<= 1) s += __shfl_xor(s, m, 64);
  const float mu = s * (1.0f / DDIM);
  float a0 = v0.x - mu, a1 = v0.y - mu, a2 = v0.z - mu, a3 = v0.w - mu;
  float a4 = v1.x - mu, a5 = v1.y - mu, a6 = v1.z - mu, a7 = v1.w - mu;
  float q = a0*a0 + a1*a1 + a2*a2 + a3*a3 + a4*a4 + a5*a5 + a6*a6 + a7*a7;
#pragma unroll
  for (int m = 1; m < 64; m <<= 1) q += __shfl_xor(q, m, 64);
  const float inv = rsqrtf(q * (1.0f / DDIM) + LN_EPS);
  const float4* wr = (const float4*)lnw;
  const float4* br = (const float4*)lnb;
  float4 w0 = wr[2*lane], w1 = wr[2*lane+1];
  float4 b0 = br[2*lane], b1 = br[2*lane+1];
  const float y0 = a0*inv*w0.x + b0.x, y1 = a1*inv*w0.y + b0.y;
  const float y2 = a2*inv*w0.z + b0.z, y3 = a3*inv*w0.w + b0.w;
  const float y4 = a4*inv*w1.x + b1.x, y5 = a5*inv*w1.y + b1.y;
  const float y6 = a6*inv*w1.z + b1.z, y7 = a7*inv*w1.w + b1.w;
  ((float4*)xs[wave])[2*lane]   = make_float4(y0, y1, y2, y3);
  ((float4*)xs[wave])[2*lane+1] = make_float4(y4, y5, y6, y7);

  const unsigned int count = cnt[row];
  double bs = 1e300;
  int bi = 0x7FFFFFFF;
  if (count <= CAND_MAX) {
    // lane i holds candidate i; filter by stored approximate score
    float si = 1e30f;
    int   ci = 0x7FFFFFFF;
    if (lane < (int)count) {
      si = candS[(size_t)row * CAND_MAX + lane];
      ci = candI[(size_t)row * CAND_MAX + lane];
    }
    float bsbf = si;
#pragma unroll
    for (int m = 1; m < 64; m <<= 1) bsbf = fminf(bsbf, __shfl_xor(bsbf, m, 64));
    unsigned long long mask = __ballot(si <= bsbf + RESCORE_WIN);
    while (mask) {
      const int l = __ffsll((long long)mask) - 1;
      mask &= mask - 1;
      const int n = __shfl(ci, l, 64);
      const float4* gr = (const float4*)(Gt + (size_t)n * DDIM);
      float4 g0 = gr[2*lane], g1 = gr[2*lane+1];
      float p = y0*g0.x;
      p = fmaf(y1, g0.y, p); p = fmaf(y2, g0.z, p); p = fmaf(y3, g0.w, p);
      p = fmaf(y4, g1.x, p); p = fmaf(y5, g1.y, p); p = fmaf(y6, g1.z, p);
      p = fmaf(y7, g1.w, p);
#pragma unroll
      for (int m = 1; m < 64; m <<= 1) p += __shfl_xor(p, m, 64);
      double sc = csq_d[n] - 2.0 * (double)p;
      if (sc < bs || (sc == bs && n < bi)) { bs = sc; bi = n; }
    }
    if (lane == 0) out[row] = bi;
  } else {
    // overflow: exact scan of all columns for this row (rare)
    for (int n = lane; n < CDIM; n += 64) {
      const float* g = Gt + (size_t)n * DDIM;
      float p = 0.f;
      for (int d = 0; d < DDIM; ++d) p = fmaf(xs[wave][d], g[d], p);
      double sc = csq_d[n] - 2.0 * (double)p;
      if (sc < bs || (sc == bs && n < bi)) { bs = sc; bi = n; }
    }
#pragma unroll
    for (int m = 1; m < 64; m <<= 1) {
      double os = __shfl_xor(bs, m, 64);
      int oi = __shfl_xor(bi, m, 64);
      if (os < bs || (os == bs && oi < bi)) { bs = os; bi = oi; }
    }
    if (lane == 0) out[row] = bi;
  }
}

extern "C" void kernel_launch(void* const* d_in, const int* in_sizes, int n_in,
                              void* d_out, int out_size, void* d_ws, size_t ws_size,
                              hipStream_t stream) {
  const float* x   = (const float*)d_in[0];
  const float* lnw = (const float*)d_in[1];
  const float* lnb = (const float*)d_in[2];
  const float* W   = (const float*)d_in[3];
  const float* cb  = (const float*)d_in[4];
  int* out = (int*)d_out;

  char* ws = (char*)d_ws;
  size_t off = 0;
  __hip_bfloat16* xb  = (__hip_bfloat16*)(ws + off); off += (size_t)MROWS * DDIM * 2;     // 16MB
  float*          Gt  = (float*)(ws + off);          off += (size_t)CDIM * DDIM * 4;      // 16MB
  __hip_bfloat16* Gtb = (__hip_bfloat16*)(ws + off); off += (size_t)CDIM * DDIM * 2;      // 8MB
  float*          csqf= (float*)(ws + off);          off += (size_t)CDIM * 4;
  double*         csqd= (double*)(ws + off);         off += (size_t)CDIM * 8;
  unsigned int*   cnt = (unsigned int*)(ws + off);   off += (size_t)MROWS * 4;
  unsigned int*   rmin= (unsigned int*)(ws + off);   off += (size_t)MROWS * 4;
  int*            candI=(int*)(ws + off);            off += (size_t)MROWS * CAND_MAX * 4; // 4MB
  float*          candS=(float*)(ws + off);          off += (size_t)MROWS * CAND_MAX * 4; // 4MB

  k_ln<<<MROWS / 4, 256, 0, stream>>>(x, lnw, lnb, xb, cnt, rmin);
  k_csq<<<CDIM / 256, 256, 0, stream>>>(cb, csqf, csqd);
  k_gproj<<<dim3(CDIM / 128, DDIM / 128), dim3(16, 16), 0, stream>>>(W, cb, Gt, Gtb);
  k_score<<<(MROWS / 128) * (CDIM / 256), 512, 0, stream>>>(xb, Gtb, csqf, rmin, cnt, candI, candS);
  k_fixup<<<MROWS / 4, 256, 0, stream>>>(x, lnw, lnb, Gt, csqd, cnt, candI, candS, out);
}